// Round 2
// baseline (557.343 us; speedup 1.0000x reference)
//
#include <hip/hip_runtime.h>
#include <stdint.h>

typedef unsigned int u32;
typedef unsigned long long u64;
typedef uint16_t u16;

typedef short bf16x8 __attribute__((ext_vector_type(8)));
typedef float f32x4 __attribute__((ext_vector_type(4)));

// Problem constants: B=32, D=1024, N=65536, K=4096, H=8, hd=128
// Factorized attention: scores = (q@Wk_h^T)@subset^T ; ctx = ((attn@subset)@Wv_h)+bv

__device__ __forceinline__ float bf2f(u16 x) { return __uint_as_float(((u32)x) << 16); }
__device__ __forceinline__ u16 f2bf(float f) {
    u32 u = __float_as_uint(f);
    return (u16)((u + 0x7FFF + ((u >> 16) & 1)) >> 16);
}

// ================= top-k via histogram radix-select =================
// key = (descending-transformed fp32 bits << 32) | index ; ascending u64 == top-k order
// scctl: [0]=threshold bin, [1]=S (count strictly above bin), [2]=strict ctr, [3]=boundary ctr

__global__ __launch_bounds__(256) void init_kernel(const float* __restrict__ prio,
                                                   u64* __restrict__ keys,
                                                   u32* __restrict__ hist,
                                                   u64* __restrict__ cand,
                                                   u32* __restrict__ scctl) {
    int i = blockIdx.x * 256 + threadIdx.x; // 65536
    u32 fb = __float_as_uint(prio[i]);
    u32 s = (fb & 0x80000000u) ? ~fb : (fb | 0x80000000u);
    keys[i] = ((u64)(~s) << 32) | (u64)i;
    hist[i] = 0;
    if (i < 8192) cand[i] = ~0ull;   // pad both sort regions with +inf keys
    if (i < 4) scctl[i] = 0;
}

__global__ __launch_bounds__(256) void hist_kernel(const u64* __restrict__ keys,
                                                   u32* __restrict__ hist) {
    int i = blockIdx.x * 256 + threadIdx.x;
    atomicAdd(&hist[(u32)(keys[i] >> 48)], 1u);
}

__global__ __launch_bounds__(1024) void scan_kernel(const u32* __restrict__ hist,
                                                    u32* __restrict__ scctl) {
    int t = threadIdx.x;
    int base = t * 64;
    const uint4* hp = (const uint4*)(hist + base);
    u32 s = 0;
#pragma unroll
    for (int i = 0; i < 16; ++i) {
        uint4 h4 = hp[i];
        s += h4.x + h4.y + h4.z + h4.w;
    }
    u32 inc = s; // inclusive scan within wave
    for (int o = 1; o < 64; o <<= 1) {
        u32 v = __shfl_up(inc, o);
        if ((t & 63) >= o) inc += v;
    }
    __shared__ u32 ws[16];
    if ((t & 63) == 63) ws[t >> 6] = inc;
    __syncthreads();
    if (t == 0) {
        u32 a = 0;
        for (int wv = 0; wv < 16; ++wv) { u32 x = ws[wv]; ws[wv] = a; a += x; }
    }
    __syncthreads();
    u32 incl = inc + ws[t >> 6];
    u32 excl = incl - s;
    if (excl < 4096u && incl >= 4096u) { // unique owner thread
        u32 cum = excl;
        for (int i = 0; i < 64; ++i) {
            u32 c = hist[base + i];
            if (cum + c >= 4096u) { scctl[0] = (u32)(base + i); scctl[1] = cum; break; }
            cum += c;
        }
    }
}

__global__ __launch_bounds__(256) void compact_kernel(const u64* __restrict__ keys,
                                                      u64* __restrict__ cand,
                                                      u32* __restrict__ scctl) {
    int i = blockIdx.x * 256 + threadIdx.x;
    u64 k = keys[i];
    u32 bin = (u32)(k >> 48);
    u32 Tb = scctl[0];
    if (bin < Tb) {
        u32 p = atomicAdd(&scctl[2], 1u);
        cand[p] = k; // strict region [0,4096)
    } else if (bin == Tb) {
        u32 p = atomicAdd(&scctl[3], 1u);
        if (p < 4096u) cand[4096 + p] = k; // boundary region [4096,8192)
    }
}

// register-resident ascending bitonic sort of 4096 u64; 4 elems/thread.
// j>=256: LDS exchange (10 phases total); 4<=j<=128: shfl_xor; j<=2: register-local.
// block 0 = strict region, block 1 = boundary region.
__global__ __launch_bounds__(1024) void sort4096_kernel(u64* __restrict__ cand) {
    __shared__ u64 sh[4096];
    u64* src = cand + (size_t)blockIdx.x * 4096;
    int t = threadIdx.x;
    u64 v[4];
#pragma unroll
    for (int s = 0; s < 4; ++s) v[s] = src[t * 4 + s];
    for (int k = 2; k <= 4096; k <<= 1) {
        for (int j = k >> 1; j >= 1; j >>= 1) {
            if (j >= 256) {
                __syncthreads(); // protect prior readers
#pragma unroll
                for (int s = 0; s < 4; ++s) sh[t * 4 + s] = v[s];
                __syncthreads();
#pragma unroll
                for (int s = 0; s < 4; ++s) {
                    int i = t * 4 + s;
                    u64 p = sh[i ^ j];
                    bool keepmin = (((i & k) == 0) == ((i & j) == 0));
                    v[s] = keepmin ? (v[s] < p ? v[s] : p) : (v[s] > p ? v[s] : p);
                }
            } else if (j >= 4) {
                int ld = j >> 2;
#pragma unroll
                for (int s = 0; s < 4; ++s) {
                    int i = t * 4 + s;
                    u64 p = __shfl_xor(v[s], ld, 64);
                    bool keepmin = (((i & k) == 0) == ((i & j) == 0));
                    v[s] = keepmin ? (v[s] < p ? v[s] : p) : (v[s] > p ? v[s] : p);
                }
            } else if (j == 2) {
#pragma unroll
                for (int s = 0; s < 2; ++s) {
                    int i = t * 4 + s;
                    bool up = ((i & k) == 0);
                    u64 a = v[s], b = v[s + 2];
                    if ((a > b) == up) { v[s] = b; v[s + 2] = a; }
                }
            } else { // j == 1
#pragma unroll
                for (int s = 0; s < 4; s += 2) {
                    int i = t * 4 + s;
                    bool up = ((i & k) == 0);
                    u64 a = v[s], b = v[s + 1];
                    if ((a > b) == up) { v[s] = b; v[s + 1] = a; }
                }
            }
        }
    }
#pragma unroll
    for (int s = 0; s < 4; ++s) src[t * 4 + s] = v[s];
}

// ============ fused gather (fp32->bf16) + transpose: bsub [4096][1024], bsubT [1024][4096]
__global__ __launch_bounds__(256) void gather_transpose_kernel(const float* __restrict__ buffer,
                                                               const u64* __restrict__ cand,
                                                               const u32* __restrict__ scctl,
                                                               u16* __restrict__ bsub,
                                                               u16* __restrict__ bsubT) {
    int r0 = blockIdx.x * 32; // 128 blocks, 32 selected rows each
    int t = threadIdx.x;
    __shared__ u16 tile[32][65];
    __shared__ u32 rowidx[32];
    if (t < 32) {
        int row = r0 + t;
        u32 S = scctl[1];
        u64 key = ((u32)row < S) ? cand[row] : cand[4096 + row - (int)S];
        rowidx[t] = (u32)key;
    }
    __syncthreads();
    for (int c0 = 0; c0 < 1024; c0 += 64) {
        for (int s = t; s < 512; s += 256) {
            int r = s >> 4, c4 = (s & 15) * 4;
            float4 vv = *(const float4*)(buffer + (size_t)rowidx[r] * 1024 + c0 + c4);
            ushort4 o;
            o.x = f2bf(vv.x); o.y = f2bf(vv.y); o.z = f2bf(vv.z); o.w = f2bf(vv.w);
            *(ushort4*)(bsub + (size_t)(r0 + r) * 1024 + c0 + c4) = o;
            tile[r][c4] = o.x; tile[r][c4 + 1] = o.y; tile[r][c4 + 2] = o.z; tile[r][c4 + 3] = o.w;
        }
        __syncthreads();
        for (int s = t; s < 1024; s += 256) {
            int rT = s >> 4;       // column 0..63
            int cT = (s & 15) * 2; // row pair
            ushort2 o2;
            o2.x = tile[cT][rT];
            o2.y = tile[cT + 1][rT];
            *(ushort2*)(bsubT + (size_t)(c0 + rT) * 4096 + r0 + cT) = o2;
        }
        __syncthreads();
    }
}

// ===== fp32 vec-mat, 4 batches/block: out[b,n] = X[b,:]@W[:,n] + bias  (grid 8 x 16) =====
__global__ __launch_bounds__(256) void vecmat4_kernel(const float* __restrict__ X,
                                                      const float* __restrict__ W,
                                                      const float* __restrict__ bias,
                                                      float* __restrict__ out) {
    int bg = blockIdx.x, n0 = blockIdx.y * 64, t = threadIdx.x;
    __shared__ float xs[4][1024];
    __shared__ float red[4][4][64]; // [kq][bb][n]
    for (int s = t; s < 4096; s += 256) {
        int bb = s >> 10, k = s & 1023;
        xs[bb][k] = X[(bg * 4 + bb) * 1024 + k];
    }
    __syncthreads();
    int n = t & 63, kq = t >> 6;
    const float* Wp = W + (size_t)(kq * 256) * 1024 + n0 + n;
    const float* x0 = xs[0] + kq * 256;
    const float* x1 = xs[1] + kq * 256;
    const float* x2 = xs[2] + kq * 256;
    const float* x3 = xs[3] + kq * 256;
    float a0 = 0.f, a1 = 0.f, a2 = 0.f, a3 = 0.f;
#pragma unroll 8
    for (int k = 0; k < 256; ++k) {
        float w = Wp[(size_t)k * 1024];
        a0 += x0[k] * w; a1 += x1[k] * w; a2 += x2[k] * w; a3 += x3[k] * w;
    }
    red[kq][0][n] = a0; red[kq][1][n] = a1; red[kq][2][n] = a2; red[kq][3][n] = a3;
    __syncthreads();
    int bb = t >> 6;
    out[(bg * 4 + bb) * 1024 + n0 + n] =
        red[0][bb][n] + red[1][bb][n] + red[2][bb][n] + red[3][bb][n] + bias[n0 + n];
}

// ================= S1[bh,e] = sum_d q[b,h,d]*Wk[e,h*128+d]  (+ cb[bh] = q_h.bk_h) ======
__global__ __launch_bounds__(256) void s1_kernel(const float* __restrict__ qp,
                                                 const float* __restrict__ Wk,
                                                 const float* __restrict__ bk,
                                                 u16* __restrict__ S1,
                                                 float* __restrict__ cb) {
    int h = blockIdx.x, e0 = blockIdx.y * 64, t = threadIdx.x;
    __shared__ float qsh[32][128];
    __shared__ float wsh[64][132];
    for (int s = t; s < 4096; s += 256) {
        int b = s >> 7, d = s & 127;
        qsh[b][d] = qp[b * 1024 + h * 128 + d];
    }
    for (int s = t; s < 8192; s += 256) {
        int e = s >> 7, d = s & 127;
        wsh[e][d] = Wk[(size_t)(e0 + e) * 1024 + h * 128 + d];
    }
    __syncthreads();
    if (blockIdx.y == 0 && t < 32) {
        float a = 0.f;
        for (int d = 0; d < 128; ++d) a += qsh[t][d] * bk[h * 128 + d];
        cb[t * 8 + h] = a;
    }
    int e = t & 63, b0 = (t >> 6) * 8;
    float acc[8] = {0.f, 0.f, 0.f, 0.f, 0.f, 0.f, 0.f, 0.f};
#pragma unroll 4
    for (int d = 0; d < 128; d += 4) {
        float4 w = *(const float4*)&wsh[e][d];
#pragma unroll
        for (int bb = 0; bb < 8; ++bb) {
            float4 q = *(const float4*)&qsh[b0 + bb][d];
            acc[bb] += w.x * q.x + w.y * q.y + w.z * q.z + w.w * q.w;
        }
    }
#pragma unroll
    for (int bb = 0; bb < 8; ++bb)
        S1[(size_t)((b0 + bb) * 8 + h) * 1024 + e0 + e] = f2bf(acc[bb]);
}

// ================= GEMM1 (MFMA): scores[256,4096] = S1[256,1024] @ bsub^T, *scale + cb ==
__global__ __launch_bounds__(256) void gemm_scores_kernel(const u16* __restrict__ A,
                                                          const u16* __restrict__ B,
                                                          const float* __restrict__ cb,
                                                          float* __restrict__ out) {
    const int nt = blockIdx.x, mt = blockIdx.y;
    __shared__ __align__(16) u16 As[128 * 64];
    __shared__ __align__(16) u16 Bs[128 * 64];
    const int t = threadIdx.x, lane = t & 63, w = t >> 6;
    const int wm = (w >> 1) * 64, wn = (w & 1) * 64;
    const int q16 = lane >> 4, l15 = lane & 15;
    f32x4 acc[4][4];
#pragma unroll
    for (int i = 0; i < 4; i++)
#pragma unroll
        for (int j = 0; j < 4; j++) acc[i][j] = (f32x4){0.f, 0.f, 0.f, 0.f};
    const int sr = t >> 3, sc = t & 7;
    for (int kk = 0; kk < 1024; kk += 64) {
#pragma unroll
        for (int p = 0; p < 4; ++p) {
            int r = p * 32 + sr, pc = sc ^ (r & 7);
            uint4 va = *(const uint4*)(A + (size_t)(mt * 128 + r) * 1024 + kk + sc * 8);
            uint4 vb = *(const uint4*)(B + (size_t)(nt * 128 + r) * 1024 + kk + sc * 8);
            *(uint4*)&As[r * 64 + pc * 8] = va;
            *(uint4*)&Bs[r * 64 + pc * 8] = vb;
        }
        __syncthreads();
#pragma unroll
        for (int f = 0; f < 2; ++f) {
            bf16x8 a[4], b[4];
#pragma unroll
            for (int i = 0; i < 4; ++i) {
                int m = wm + i * 16 + l15;
                int pc = (f * 4 + q16) ^ (m & 7);
                a[i] = *(const bf16x8*)&As[m * 64 + pc * 8];
                int n = wn + i * 16 + l15;
                b[i] = *(const bf16x8*)&Bs[n * 64 + pc * 8];
            }
#pragma unroll
            for (int i = 0; i < 4; ++i)
#pragma unroll
                for (int j = 0; j < 4; ++j)
                    acc[i][j] = __builtin_amdgcn_mfma_f32_16x16x32_bf16(a[i], b[j], acc[i][j], 0, 0, 0);
        }
        __syncthreads();
    }
#pragma unroll
    for (int i = 0; i < 4; ++i) {
        int mbase = mt * 128 + wm + i * 16 + q16 * 4;
        float cbv[4];
#pragma unroll
        for (int r = 0; r < 4; ++r) cbv[r] = cb[mbase + r];
#pragma unroll
        for (int j = 0; j < 4; ++j) {
            int n = nt * 128 + wn + j * 16 + l15;
#pragma unroll
            for (int r = 0; r < 4; ++r)
                out[(size_t)(mbase + r) * 4096 + n] = acc[i][j][r] * 0.08838834764831845f + cbv[r];
        }
    }
}

// ================= single-pass softmax over k, emit bf16 attn =================
__global__ __launch_bounds__(256) void softmax_kernel(const float* __restrict__ scores,
                                                      u16* __restrict__ attnbf) {
    int row = blockIdx.x, t = threadIdx.x;
    __shared__ float rowsh[4096];
    __shared__ float red[4];
    const float* p = scores + (size_t)row * 4096;
    float m = -1e30f;
    for (int i = t; i < 4096; i += 256) {
        float v = p[i];
        rowsh[i] = v;
        m = fmaxf(m, v);
    }
#pragma unroll
    for (int o = 32; o >= 1; o >>= 1) m = fmaxf(m, __shfl_xor(m, o));
    if ((t & 63) == 0) red[t >> 6] = m;
    __syncthreads();
    m = fmaxf(fmaxf(red[0], red[1]), fmaxf(red[2], red[3]));
    float sum = 0.f;
    for (int i = t; i < 4096; i += 256) {
        float e = __expf(rowsh[i] - m);
        rowsh[i] = e;
        sum += e;
    }
#pragma unroll
    for (int o = 32; o >= 1; o >>= 1) sum += __shfl_xor(sum, o);
    __syncthreads();
    if ((t & 63) == 0) red[t >> 6] = sum;
    __syncthreads();
    sum = red[0] + red[1] + red[2] + red[3];
    float inv = 1.0f / sum;
    for (int i = t; i < 4096; i += 256)
        attnbf[(size_t)row * 4096 + i] = f2bf(rowsh[i] * inv);
}

__global__ void attn_avg_kernel(const u16* __restrict__ attnbf,
                                float* __restrict__ out) {
    int g = blockIdx.x * 256 + threadIdx.x; // 131072
    int b = g >> 12, k = g & 4095;
    float s = 0.f;
#pragma unroll
    for (int h = 0; h < 8; ++h) s += bf2f(attnbf[(size_t)(b * 8 + h) * 4096 + k]);
    out[g] = s * 0.125f;
}

// ========== GEMM2 (MFMA, split-K 8): Tpart[ks][256][1024] = attnbf @ bsub (chunk) ======
__global__ __launch_bounds__(256) void gemm_t_kernel(const u16* __restrict__ A,
                                                     const u16* __restrict__ B,
                                                     float* __restrict__ part) {
    const int nt = blockIdx.x, mt = blockIdx.y, ks = blockIdx.z;
    __shared__ __align__(16) u16 As[128 * 64];
    __shared__ __align__(16) u16 Bs[128 * 64];
    const int t = threadIdx.x, lane = t & 63, w = t >> 6;
    const int wm = (w >> 1) * 64, wn = (w & 1) * 64;
    const int q16 = lane >> 4, l15 = lane & 15;
    f32x4 acc[4][4];
#pragma unroll
    for (int i = 0; i < 4; i++)
#pragma unroll
        for (int j = 0; j < 4; j++) acc[i][j] = (f32x4){0.f, 0.f, 0.f, 0.f};
    const int sr = t >> 3, sc = t & 7;
    const int k0 = ks * 512;
    for (int kk = k0; kk < k0 + 512; kk += 64) {
#pragma unroll
        for (int p = 0; p < 4; ++p) {
            int r = p * 32 + sr, pc = sc ^ (r & 7);
            uint4 va = *(const uint4*)(A + (size_t)(mt * 128 + r) * 4096 + kk + sc * 8);
            uint4 vb = *(const uint4*)(B + (size_t)(nt * 128 + r) * 4096 + kk + sc * 8);
            *(uint4*)&As[r * 64 + pc * 8] = va;
            *(uint4*)&Bs[r * 64 + pc * 8] = vb;
        }
        __syncthreads();
#pragma unroll
        for (int f = 0; f < 2; ++f) {
            bf16x8 a[4], b[4];
#pragma unroll
            for (int i = 0; i < 4; ++i) {
                int m = wm + i * 16 + l15;
                int pc = (f * 4 + q16) ^ (m & 7);
                a[i] = *(const bf16x8*)&As[m * 64 + pc * 8];
                int n = wn + i * 16 + l15;
                b[i] = *(const bf16x8*)&Bs[n * 64 + pc * 8];
            }
#pragma unroll
            for (int i = 0; i < 4; ++i)
#pragma unroll
                for (int j = 0; j < 4; ++j)
                    acc[i][j] = __builtin_amdgcn_mfma_f32_16x16x32_bf16(a[i], b[j], acc[i][j], 0, 0, 0);
        }
        __syncthreads();
    }
#pragma unroll
    for (int i = 0; i < 4; ++i) {
        int mbase = mt * 128 + wm + i * 16 + q16 * 4;
#pragma unroll
        for (int j = 0; j < 4; ++j) {
            int n = nt * 128 + wn + j * 16 + l15;
#pragma unroll
            for (int r = 0; r < 4; ++r)
                part[(size_t)(ks * 256 + mbase + r) * 1024 + n] = acc[i][j][r];
        }
    }
}

// === ctx[b,n] = sum_e (sum_ks Tpart[ks][bh][e]) * Wv[e][n] + bv[n], 4 batches/block ===
__global__ __launch_bounds__(256) void ctx_reduce4_kernel(const float* __restrict__ part,
                                                          const float* __restrict__ Wv,
                                                          const float* __restrict__ bv,
                                                          float* __restrict__ ctx) {
    int bg = blockIdx.x, n0 = blockIdx.y * 64, t = threadIdx.x;
    int h = n0 >> 7;
    __shared__ float ts[4][1024];
    __shared__ float red[4][4][64];
    for (int s = t; s < 4096; s += 256) {
        int bb = s >> 10, e = s & 1023;
        int bh = (bg * 4 + bb) * 8 + h;
        float a = 0.f;
#pragma unroll
        for (int ks = 0; ks < 8; ++ks) a += part[(size_t)(ks * 256 + bh) * 1024 + e];
        ts[bb][e] = a;
    }
    __syncthreads();
    int n = t & 63, kq = t >> 6;
    const float* Wp = Wv + (size_t)(kq * 256) * 1024 + n0 + n;
    const float* x0 = ts[0] + kq * 256;
    const float* x1 = ts[1] + kq * 256;
    const float* x2 = ts[2] + kq * 256;
    const float* x3 = ts[3] + kq * 256;
    float a0 = 0.f, a1 = 0.f, a2 = 0.f, a3 = 0.f;
#pragma unroll 8
    for (int k = 0; k < 256; ++k) {
        float w = Wp[(size_t)k * 1024];
        a0 += x0[k] * w; a1 += x1[k] * w; a2 += x2[k] * w; a3 += x3[k] * w;
    }
    red[kq][0][n] = a0; red[kq][1][n] = a1; red[kq][2][n] = a2; red[kq][3][n] = a3;
    __syncthreads();
    int bb = t >> 6;
    ctx[(bg * 4 + bb) * 1024 + n0 + n] =
        red[0][bb][n] + red[1][bb][n] + red[2][bb][n] + red[3][bb][n] + bv[n0 + n];
}

extern "C" void kernel_launch(void* const* d_in, const int* in_sizes, int n_in,
                              void* d_out, int out_size, void* d_ws, size_t ws_size,
                              hipStream_t stream) {
    const float* query  = (const float*)d_in[0];
    const float* buffer = (const float*)d_in[1];
    const float* prio   = (const float*)d_in[2];
    const float* Wq     = (const float*)d_in[3];
    const float* bq     = (const float*)d_in[4];
    const float* Wk     = (const float*)d_in[5];
    const float* bk     = (const float*)d_in[6];
    const float* Wv     = (const float*)d_in[7];
    const float* bv     = (const float*)d_in[8];
    const float* Wo     = (const float*)d_in[9];
    const float* bo     = (const float*)d_in[10];

    char* w = (char*)d_ws;
    auto alloc = [&](size_t bytes) {
        char* p = w;
        w += (bytes + 255) & ~(size_t)255;
        return p;
    };
    u64* keys    = (u64*)alloc((size_t)65536 * 8);              // 512 KB
    u32* hist    = (u32*)alloc((size_t)65536 * 4);              // 256 KB
    u32* scctl   = (u32*)alloc(16);                             // control block
    u64* cand    = (u64*)alloc((size_t)8192 * 8);               // 64 KB (strict | boundary)
    u16* bsub    = (u16*)alloc((size_t)4096 * 1024 * 2);        // 8 MB
    u16* bsubT   = (u16*)alloc((size_t)1024 * 4096 * 2);        // 8 MB
    float* qp    = (float*)alloc((size_t)32 * 1024 * 4);        // 128 KB
    u16* S1bf    = (u16*)alloc((size_t)256 * 1024 * 2);         // 512 KB
    float* cbb   = (float*)alloc((size_t)256 * 4);              // 1 KB
    float* scores= (float*)alloc((size_t)256 * 4096 * 4);       // 4 MB
    u16* attnbf  = (u16*)alloc((size_t)256 * 4096 * 2);         // 2 MB
    float* Tpart = (float*)alloc((size_t)8 * 256 * 1024 * 4);   // 8 MB
    float* ctx   = (float*)alloc((size_t)32 * 1024 * 4);        // 128 KB

    float* out_retrieved = (float*)d_out;            // [32,1024]
    float* out_attnavg   = (float*)d_out + 32768;    // [32,4096]

    // 1. top-k (exact jax.lax.top_k semantics incl. tie order) — 5 dispatches
    init_kernel<<<256, 256, 0, stream>>>(prio, keys, hist, cand, scctl);
    hist_kernel<<<256, 256, 0, stream>>>(keys, hist);
    scan_kernel<<<1, 1024, 0, stream>>>(hist, scctl);
    compact_kernel<<<256, 256, 0, stream>>>(keys, cand, scctl);
    sort4096_kernel<<<2, 1024, 0, stream>>>(cand);

    // 2. fused gather+convert+transpose; q projection
    gather_transpose_kernel<<<128, 256, 0, stream>>>(buffer, cand, scctl, bsub, bsubT);
    vecmat4_kernel<<<dim3(8, 16), 256, 0, stream>>>(query, Wq, bq, qp);

    // 3. scores = (q@Wk_h^T) @ subset^T  (small fp32 + one MFMA GEMM)
    s1_kernel<<<dim3(8, 16), 256, 0, stream>>>(qp, Wk, bk, S1bf, cbb);
    gemm_scores_kernel<<<dim3(32, 2), 256, 0, stream>>>(S1bf, bsub, cbb, scores);

    // 4. softmax (single-pass, emits bf16) + head-average output
    softmax_kernel<<<256, 256, 0, stream>>>(scores, attnbf);
    attn_avg_kernel<<<512, 256, 0, stream>>>(attnbf, out_attnavg);

    // 5. ctx = ((attn @ subset) @ Wv_h) + bv  (split-K MFMA GEMM + fp32 reduce-matvec)
    gemm_t_kernel<<<dim3(8, 2, 8), 256, 0, stream>>>(attnbf, bsubT, Tpart);
    ctx_reduce4_kernel<<<dim3(8, 16), 256, 0, stream>>>(Tpart, Wv, bv, ctx);

    // 6. output projection
    vecmat4_kernel<<<dim3(8, 16), 256, 0, stream>>>(ctx, Wo, bo, out_retrieved);
}

// Round 6
// 511.494 us; speedup vs baseline: 1.0896x; 1.0896x over previous
//
#include <hip/hip_runtime.h>
#include <stdint.h>

typedef unsigned int u32;
typedef unsigned long long u64;
typedef uint16_t u16;

typedef short bf16x8 __attribute__((ext_vector_type(8)));
typedef float f32x4 __attribute__((ext_vector_type(4)));

// Problem constants: B=32, D=1024, N=65536, K=4096, H=8, hd=128
// Factorized attention: scores = (q@Wk_h^T)@subset^T ; ctx = ((attn@subset)@Wv_h)+bv
// bk drops out entirely: q.bk is constant along the softmax axis.

__device__ __forceinline__ float bf2f(u16 x) { return __uint_as_float(((u32)x) << 16); }
__device__ __forceinline__ u16 f2bf(float f) {
    u32 u = __float_as_uint(f);
    return (u16)((u + 0x7FFF + ((u >> 16) & 1)) >> 16);
}
__device__ __forceinline__ u32 prio_key_hi(float pv) {
    u32 fb = __float_as_uint(pv);
    u32 s = (fb & 0x80000000u) ? ~fb : (fb | 0x80000000u);
    return ~s; // descending-sortable transform
}

// ======== fp32 vec-mat body, 4 batches/block: out[b,n] = X[b,:]@W[:,n] + bias ========
__device__ __forceinline__ void vecmat4_body(const float* __restrict__ X,
                                             const float* __restrict__ W,
                                             const float* __restrict__ bias,
                                             float* __restrict__ out,
                                             int bg, int n0, int t,
                                             float (*xs)[1024], float (*red)[4][64]) {
    for (int s = t; s < 4096; s += 256) {
        int bb = s >> 10, k = s & 1023;
        xs[bb][k] = X[(bg * 4 + bb) * 1024 + k];
    }
    __syncthreads();
    int n = t & 63, kq = t >> 6;
    const float* Wp = W + (size_t)(kq * 256) * 1024 + n0 + n;
    const float* x0 = xs[0] + kq * 256;
    const float* x1 = xs[1] + kq * 256;
    const float* x2 = xs[2] + kq * 256;
    const float* x3 = xs[3] + kq * 256;
    float a0 = 0.f, a1 = 0.f, a2 = 0.f, a3 = 0.f;
#pragma unroll 8
    for (int k = 0; k < 256; ++k) {
        float w = Wp[(size_t)k * 1024];
        a0 += x0[k] * w; a1 += x1[k] * w; a2 += x2[k] * w; a3 += x3[k] * w;
    }
    red[kq][0][n] = a0; red[kq][1][n] = a1; red[kq][2][n] = a2; red[kq][3][n] = a3;
    __syncthreads();
    int bb = t >> 6;
    out[(bg * 4 + bb) * 1024 + n0 + n] =
        red[0][bb][n] + red[1][bb][n] + red[2][bb][n] + red[3][bb][n] + bias[n0 + n];
}

// ================= K1: init (hist zero, cand pad, scctl zero) ∥ qproj =================
// scctl: [0]=threshold bin [1]=strict count S [2]=strict ctr [3]=boundary ctr
__global__ __launch_bounds__(256) void k1_init_qproj(const float* __restrict__ query,
                                                     const float* __restrict__ Wq,
                                                     const float* __restrict__ bq,
                                                     float* __restrict__ qp,
                                                     u32* __restrict__ hist,
                                                     u64* __restrict__ cand,
                                                     u32* __restrict__ scctl) {
    __shared__ float xs[4][1024];
    __shared__ float red[4][4][64];
    int bid = blockIdx.x, t = threadIdx.x;
    if (bid < 128) {
        vecmat4_body(query, Wq, bq, qp, bid >> 4, (bid & 15) * 64, t, xs, red);
    } else {
        int id = bid - 128; // 0..255
        hist[id * 256 + t] = 0;
        if (id < 32) cand[id * 256 + t] = ~0ull; // pad both sort regions
        if (id == 32 && t < 8) scctl[t] = 0;
    }
}

// ===== K2: hist atomics (no scan — scan is a separate verified kernel) ∥ s1 =====
// s1[bh,e] = sum_d q[b,h,d]*Wk[e,h*128+d]
__global__ __launch_bounds__(256) void k2_hist_s1(const float* __restrict__ prio,
                                                  const float* __restrict__ qp,
                                                  const float* __restrict__ Wk,
                                                  u16* __restrict__ S1,
                                                  u32* __restrict__ hist) {
    __shared__ float qsh[32][128];
    __shared__ float wsh[64][132];
    int bid = blockIdx.x, t = threadIdx.x;
    if (bid < 256) {
        // ---- histogram over top-16 key bits ----
        int i = bid * 256 + t;
        u32 ds = prio_key_hi(prio[i]);
        atomicAdd(&hist[ds >> 16], 1u);
    } else {
        // ---- s1 ----
        int id = bid - 256; // 0..127
        int h = id & 7, e0 = (id >> 3) * 64;
        for (int s = t; s < 4096; s += 256) {
            int b = s >> 7, d = s & 127;
            qsh[b][d] = qp[b * 1024 + h * 128 + d];
        }
        for (int s = t; s < 8192; s += 256) {
            int e = s >> 7, d = s & 127;
            wsh[e][d] = Wk[(size_t)(e0 + e) * 1024 + h * 128 + d];
        }
        __syncthreads();
        int e = t & 63, b0 = (t >> 6) * 8;
        float acc[8] = {0.f, 0.f, 0.f, 0.f, 0.f, 0.f, 0.f, 0.f};
#pragma unroll 4
        for (int d = 0; d < 128; d += 4) {
            float4 w = *(const float4*)&wsh[e][d];
#pragma unroll
            for (int bb = 0; bb < 8; ++bb) {
                float4 q = *(const float4*)&qsh[b0 + bb][d];
                acc[bb] += w.x * q.x + w.y * q.y + w.z * q.z + w.w * q.w;
            }
        }
#pragma unroll
        for (int bb = 0; bb < 8; ++bb)
            S1[(size_t)((b0 + bb) * 8 + h) * 1024 + e0 + e] = f2bf(acc[bb]);
    }
}

// ============ K3: single-block scan to find threshold bin (verified R1/R2) ============
__global__ __launch_bounds__(1024) void scan_kernel(const u32* __restrict__ hist,
                                                    u32* __restrict__ scctl) {
    int t = threadIdx.x;
    int base = t * 64;
    const uint4* hp = (const uint4*)(hist + base);
    u32 s = 0;
#pragma unroll
    for (int i = 0; i < 16; ++i) {
        uint4 h4 = hp[i];
        s += h4.x + h4.y + h4.z + h4.w;
    }
    u32 inc = s; // inclusive scan within wave
    for (int o = 1; o < 64; o <<= 1) {
        u32 v = __shfl_up(inc, o);
        if ((t & 63) >= o) inc += v;
    }
    __shared__ u32 ws[16];
    if ((t & 63) == 63) ws[t >> 6] = inc;
    __syncthreads();
    if (t == 0) {
        u32 a = 0;
        for (int wv = 0; wv < 16; ++wv) { u32 x = ws[wv]; ws[wv] = a; a += x; }
    }
    __syncthreads();
    u32 incl = inc + ws[t >> 6];
    u32 excl = incl - s;
    if (excl < 4096u && incl >= 4096u) { // unique owner thread
        u32 cum = excl;
        for (int i = 0; i < 64; ++i) {
            u32 c = hist[base + i];
            if (cum + c >= 4096u) { scctl[0] = (u32)(base + i); scctl[1] = cum; break; }
            cum += c;
        }
    }
}

// ================= K4: compact (recompute keys) =================
__global__ __launch_bounds__(256) void k4_compact(const float* __restrict__ prio,
                                                  u64* __restrict__ cand,
                                                  u32* __restrict__ scctl) {
    int i = blockIdx.x * 256 + threadIdx.x;
    u32 ds = prio_key_hi(prio[i]);
    u64 k = ((u64)ds << 32) | (u64)i;
    u32 bin = ds >> 16;
    u32 Tb = scctl[0];
    if (bin < Tb) {
        cand[atomicAdd(&scctl[2], 1u)] = k; // strict region [0,4096)
    } else if (bin == Tb) {
        u32 p = atomicAdd(&scctl[3], 1u);
        if (p < 4096u) cand[4096 + p] = k; // boundary region [4096,8192)
    }
}

// K5: register-resident ascending bitonic sort of 4096 u64; 4 elems/thread (verified R2).
__global__ __launch_bounds__(1024) void sort4096_kernel(u64* __restrict__ cand) {
    __shared__ u64 sh[4096];
    u64* src = cand + (size_t)blockIdx.x * 4096;
    int t = threadIdx.x;
    u64 v[4];
#pragma unroll
    for (int s = 0; s < 4; ++s) v[s] = src[t * 4 + s];
    for (int k = 2; k <= 4096; k <<= 1) {
        for (int j = k >> 1; j >= 1; j >>= 1) {
            if (j >= 256) {
                __syncthreads();
#pragma unroll
                for (int s = 0; s < 4; ++s) sh[t * 4 + s] = v[s];
                __syncthreads();
#pragma unroll
                for (int s = 0; s < 4; ++s) {
                    int i = t * 4 + s;
                    u64 p = sh[i ^ j];
                    bool keepmin = (((i & k) == 0) == ((i & j) == 0));
                    v[s] = keepmin ? (v[s] < p ? v[s] : p) : (v[s] > p ? v[s] : p);
                }
            } else if (j >= 4) {
                int ld = j >> 2;
#pragma unroll
                for (int s = 0; s < 4; ++s) {
                    int i = t * 4 + s;
                    u64 p = __shfl_xor(v[s], ld, 64);
                    bool keepmin = (((i & k) == 0) == ((i & j) == 0));
                    v[s] = keepmin ? (v[s] < p ? v[s] : p) : (v[s] > p ? v[s] : p);
                }
            } else if (j == 2) {
#pragma unroll
                for (int s = 0; s < 2; ++s) {
                    int i = t * 4 + s;
                    bool up = ((i & k) == 0);
                    u64 a = v[s], b = v[s + 2];
                    if ((a > b) == up) { v[s] = b; v[s + 2] = a; }
                }
            } else {
#pragma unroll
                for (int s = 0; s < 4; s += 2) {
                    int i = t * 4 + s;
                    bool up = ((i & k) == 0);
                    u64 a = v[s], b = v[s + 1];
                    if ((a > b) == up) { v[s] = b; v[s + 1] = a; }
                }
            }
        }
    }
#pragma unroll
    for (int s = 0; s < 4; ++s) src[t * 4 + s] = v[s];
}

// ===== K6: fused gather (fp32->bf16) + transpose; 256 blocks x 16 rows, 2 barriers =====
__global__ __launch_bounds__(256) void k6_gather(const float* __restrict__ buffer,
                                                 const u64* __restrict__ cand,
                                                 const u32* __restrict__ scctl,
                                                 u16* __restrict__ bsub,
                                                 u16* __restrict__ bsubT) {
    int r0 = blockIdx.x * 16;
    int t = threadIdx.x;
    __shared__ __align__(16) u16 tile[16][1032];
    __shared__ u32 rowidx[16];
    if (t < 16) {
        int row = r0 + t;
        u32 S = scctl[1];
        u64 key = ((u32)row < S) ? cand[row] : cand[4096 + row - (int)S];
        rowidx[t] = (u32)key;
    }
    __syncthreads();
    int r = t >> 4, cbase = (t & 15) * 4;
    u32 ridx = rowidx[r];
#pragma unroll
    for (int it = 0; it < 16; ++it) {
        int c4 = cbase + it * 64;
        float4 vv = *(const float4*)(buffer + (size_t)ridx * 1024 + c4);
        ushort4 o;
        o.x = f2bf(vv.x); o.y = f2bf(vv.y); o.z = f2bf(vv.z); o.w = f2bf(vv.w);
        *(ushort4*)(bsub + (size_t)(r0 + r) * 1024 + c4) = o;
        *(ushort4*)&tile[r][c4] = o;
    }
    __syncthreads();
#pragma unroll
    for (int it = 0; it < 16; ++it) {
        int wi = it * 256 + t;   // 0..4095
        int e = wi >> 2, kg = wi & 3;
        ushort4 o;
        o.x = tile[kg * 4 + 0][e];
        o.y = tile[kg * 4 + 1][e];
        o.z = tile[kg * 4 + 2][e];
        o.w = tile[kg * 4 + 3][e];
        *(ushort4*)(bsubT + (size_t)e * 4096 + r0 + kg * 4) = o;
    }
}

// ==== K7: GEMM1 (MFMA, split-K 2): spart[ks][256][4096] = S1 @ bsub^T (raw, no scale) ====
__global__ __launch_bounds__(256) void k7_gemm_scores(const u16* __restrict__ A,
                                                      const u16* __restrict__ B,
                                                      float* __restrict__ spart) {
    const int nt = blockIdx.x, mt = blockIdx.y, ks = blockIdx.z;
    __shared__ __align__(16) u16 As[128 * 64];
    __shared__ __align__(16) u16 Bs[128 * 64];
    const int t = threadIdx.x, lane = t & 63, w = t >> 6;
    const int wm = (w >> 1) * 64, wn = (w & 1) * 64;
    const int q16 = lane >> 4, l15 = lane & 15;
    f32x4 acc[4][4];
#pragma unroll
    for (int i = 0; i < 4; i++)
#pragma unroll
        for (int j = 0; j < 4; j++) acc[i][j] = (f32x4){0.f, 0.f, 0.f, 0.f};
    const int sr = t >> 3, sc = t & 7;
    const int k0 = ks * 512;
    for (int kk = k0; kk < k0 + 512; kk += 64) {
#pragma unroll
        for (int p = 0; p < 4; ++p) {
            int r = p * 32 + sr, pc = sc ^ (r & 7);
            uint4 va = *(const uint4*)(A + (size_t)(mt * 128 + r) * 1024 + kk + sc * 8);
            uint4 vb = *(const uint4*)(B + (size_t)(nt * 128 + r) * 1024 + kk + sc * 8);
            *(uint4*)&As[r * 64 + pc * 8] = va;
            *(uint4*)&Bs[r * 64 + pc * 8] = vb;
        }
        __syncthreads();
#pragma unroll
        for (int f = 0; f < 2; ++f) {
            bf16x8 a[4], b[4];
#pragma unroll
            for (int i = 0; i < 4; ++i) {
                int m = wm + i * 16 + l15;
                int pc = (f * 4 + q16) ^ (m & 7);
                a[i] = *(const bf16x8*)&As[m * 64 + pc * 8];
                int n = wn + i * 16 + l15;
                b[i] = *(const bf16x8*)&Bs[n * 64 + pc * 8];
            }
#pragma unroll
            for (int i = 0; i < 4; ++i)
#pragma unroll
                for (int j = 0; j < 4; ++j)
                    acc[i][j] = __builtin_amdgcn_mfma_f32_16x16x32_bf16(a[i], b[j], acc[i][j], 0, 0, 0);
        }
        __syncthreads();
    }
#pragma unroll
    for (int i = 0; i < 4; ++i) {
        int mbase = mt * 128 + wm + i * 16 + q16 * 4;
#pragma unroll
        for (int j = 0; j < 4; ++j) {
            int n = nt * 128 + wn + j * 16 + l15;
#pragma unroll
            for (int r = 0; r < 4; ++r)
                spart[(size_t)(ks * 256 + mbase + r) * 4096 + n] = acc[i][j][r];
        }
    }
}

// ==== K8: softmax over k (sums split-K partials, applies scale), emits bf16 attn ====
__global__ __launch_bounds__(256) void k8_softmax(const float* __restrict__ spart,
                                                  u16* __restrict__ attnbf) {
    int row = blockIdx.x, t = threadIdx.x;
    __shared__ float rowsh[4096];
    __shared__ float red[4];
    const float* p0 = spart + (size_t)row * 4096;
    const float* p1 = spart + (size_t)(256 + row) * 4096;
    float m = -1e30f;
    for (int i = t; i < 4096; i += 256) {
        float v = (p0[i] + p1[i]) * 0.08838834764831845f;
        rowsh[i] = v;
        m = fmaxf(m, v);
    }
#pragma unroll
    for (int o = 32; o >= 1; o >>= 1) m = fmaxf(m, __shfl_xor(m, o));
    if ((t & 63) == 0) red[t >> 6] = m;
    __syncthreads();
    m = fmaxf(fmaxf(red[0], red[1]), fmaxf(red[2], red[3]));
    float sum = 0.f;
    for (int i = t; i < 4096; i += 256) {
        float e = __expf(rowsh[i] - m);
        rowsh[i] = e;
        sum += e;
    }
#pragma unroll
    for (int o = 32; o >= 1; o >>= 1) sum += __shfl_xor(sum, o);
    __syncthreads();
    if ((t & 63) == 0) red[t >> 6] = sum;
    __syncthreads();
    sum = red[0] + red[1] + red[2] + red[3];
    float inv = 1.0f / sum;
    for (int i = t; i < 4096; i += 256)
        attnbf[(size_t)row * 4096 + i] = f2bf(rowsh[i] * inv);
}

// ==== K9: GEMM2 (MFMA, split-K 8): Tpart = attnbf @ bsubT  ∥  attn_avg output ====
__global__ __launch_bounds__(256) void k9_gemmt_avg(const u16* __restrict__ A,
                                                    const u16* __restrict__ B,
                                                    float* __restrict__ part,
                                                    float* __restrict__ avgout) {
    __shared__ __align__(16) u16 As[128 * 64];
    __shared__ __align__(16) u16 Bs[128 * 64];
    int bid = blockIdx.x, t = threadIdx.x;
    if (bid >= 128) {
        int g = (bid - 128) * 256 + t; // 131072
        int b = g >> 12, k = g & 4095;
        float s = 0.f;
#pragma unroll
        for (int h = 0; h < 8; ++h) s += bf2f(A[(size_t)(b * 8 + h) * 4096 + k]);
        avgout[g] = s * 0.125f;
        return;
    }
    const int nt = bid & 7, mt = (bid >> 3) & 1, ks = bid >> 4;
    const int lane = t & 63, w = t >> 6;
    const int wm = (w >> 1) * 64, wn = (w & 1) * 64;
    const int q16 = lane >> 4, l15 = lane & 15;
    f32x4 acc[4][4];
#pragma unroll
    for (int i = 0; i < 4; i++)
#pragma unroll
        for (int j = 0; j < 4; j++) acc[i][j] = (f32x4){0.f, 0.f, 0.f, 0.f};
    const int sr = t >> 3, sc = t & 7;
    const int k0 = ks * 512;
    for (int kk = k0; kk < k0 + 512; kk += 64) {
#pragma unroll
        for (int p = 0; p < 4; ++p) {
            int r = p * 32 + sr, pc = sc ^ (r & 7);
            uint4 va = *(const uint4*)(A + (size_t)(mt * 128 + r) * 4096 + kk + sc * 8);
            uint4 vb = *(const uint4*)(B + (size_t)(nt * 128 + r) * 4096 + kk + sc * 8);
            *(uint4*)&As[r * 64 + pc * 8] = va;
            *(uint4*)&Bs[r * 64 + pc * 8] = vb;
        }
        __syncthreads();
#pragma unroll
        for (int f = 0; f < 2; ++f) {
            bf16x8 a[4], b[4];
#pragma unroll
            for (int i = 0; i < 4; ++i) {
                int m = wm + i * 16 + l15;
                int pc = (f * 4 + q16) ^ (m & 7);
                a[i] = *(const bf16x8*)&As[m * 64 + pc * 8];
                int n = wn + i * 16 + l15;
                b[i] = *(const bf16x8*)&Bs[n * 64 + pc * 8];
            }
#pragma unroll
            for (int i = 0; i < 4; ++i)
#pragma unroll
                for (int j = 0; j < 4; ++j)
                    acc[i][j] = __builtin_amdgcn_mfma_f32_16x16x32_bf16(a[i], b[j], acc[i][j], 0, 0, 0);
        }
        __syncthreads();
    }
#pragma unroll
    for (int i = 0; i < 4; ++i) {
        int mbase = mt * 128 + wm + i * 16 + q16 * 4;
#pragma unroll
        for (int j = 0; j < 4; ++j) {
            int n = nt * 128 + wn + j * 16 + l15;
#pragma unroll
            for (int r = 0; r < 4; ++r)
                part[(size_t)(ks * 256 + mbase + r) * 1024 + n] = acc[i][j][r];
        }
    }
}

// === K10: ctx[b,n] = sum_e (sum_ks Tpart[ks][bh][e]) * Wv[e][n] + bv[n], 4 batches/block ===
__global__ __launch_bounds__(256) void ctx_reduce4_kernel(const float* __restrict__ part,
                                                          const float* __restrict__ Wv,
                                                          const float* __restrict__ bv,
                                                          float* __restrict__ ctx) {
    int bg = blockIdx.x, n0 = blockIdx.y * 64, t = threadIdx.x;
    int h = n0 >> 7;
    __shared__ float ts[4][1024];
    __shared__ float red[4][4][64];
    for (int s = t; s < 4096; s += 256) {
        int bb = s >> 10, e = s & 1023;
        int bh = (bg * 4 + bb) * 8 + h;
        float a = 0.f;
#pragma unroll
        for (int ks = 0; ks < 8; ++ks) a += part[(size_t)(ks * 256 + bh) * 1024 + e];
        ts[bb][e] = a;
    }
    __syncthreads();
    int n = t & 63, kq = t >> 6;
    const float* Wp = Wv + (size_t)(kq * 256) * 1024 + n0 + n;
    const float* x0 = ts[0] + kq * 256;
    const float* x1 = ts[1] + kq * 256;
    const float* x2 = ts[2] + kq * 256;
    const float* x3 = ts[3] + kq * 256;
    float a0 = 0.f, a1 = 0.f, a2 = 0.f, a3 = 0.f;
#pragma unroll 8
    for (int k = 0; k < 256; ++k) {
        float w = Wp[(size_t)k * 1024];
        a0 += x0[k] * w; a1 += x1[k] * w; a2 += x2[k] * w; a3 += x3[k] * w;
    }
    red[kq][0][n] = a0; red[kq][1][n] = a1; red[kq][2][n] = a2; red[kq][3][n] = a3;
    __syncthreads();
    int bb = t >> 6;
    ctx[(bg * 4 + bb) * 1024 + n0 + n] =
        red[0][bb][n] + red[1][bb][n] + red[2][bb][n] + red[3][bb][n] + bv[n0 + n];
}

// ================= K11: output projection =================
__global__ __launch_bounds__(256) void k11_outproj(const float* __restrict__ ctx,
                                                   const float* __restrict__ Wo,
                                                   const float* __restrict__ bo,
                                                   float* __restrict__ out) {
    __shared__ float xs[4][1024];
    __shared__ float red[4][4][64];
    vecmat4_body(ctx, Wo, bo, out, blockIdx.x, blockIdx.y * 64, threadIdx.x, xs, red);
}

extern "C" void kernel_launch(void* const* d_in, const int* in_sizes, int n_in,
                              void* d_out, int out_size, void* d_ws, size_t ws_size,
                              hipStream_t stream) {
    const float* query  = (const float*)d_in[0];
    const float* buffer = (const float*)d_in[1];
    const float* prio   = (const float*)d_in[2];
    const float* Wq     = (const float*)d_in[3];
    const float* bq     = (const float*)d_in[4];
    const float* Wk     = (const float*)d_in[5];
    const float* Wv     = (const float*)d_in[7];
    const float* bv     = (const float*)d_in[8];
    const float* Wo     = (const float*)d_in[9];
    const float* bo     = (const float*)d_in[10];

    char* w = (char*)d_ws;
    auto alloc = [&](size_t bytes) {
        char* p = w;
        w += (bytes + 255) & ~(size_t)255;
        return p;
    };
    u32* hist    = (u32*)alloc((size_t)65536 * 4);              // 256 KB
    u32* scctl   = (u32*)alloc(32);                             // control block
    u64* cand    = (u64*)alloc((size_t)8192 * 8);               // 64 KB (strict | boundary)
    u16* bsub    = (u16*)alloc((size_t)4096 * 1024 * 2);        // 8 MB
    u16* bsubT   = (u16*)alloc((size_t)1024 * 4096 * 2);        // 8 MB
    float* qp    = (float*)alloc((size_t)32 * 1024 * 4);        // 128 KB
    u16* S1bf    = (u16*)alloc((size_t)256 * 1024 * 2);         // 512 KB
    float* spart = (float*)alloc((size_t)2 * 256 * 4096 * 4);   // 8 MB
    u16* attnbf  = (u16*)alloc((size_t)256 * 4096 * 2);         // 2 MB
    float* Tpart = (float*)alloc((size_t)8 * 256 * 1024 * 4);   // 8 MB
    float* ctx   = (float*)alloc((size_t)32 * 1024 * 4);        // 128 KB

    float* out_retrieved = (float*)d_out;            // [32,1024]
    float* out_attnavg   = (float*)d_out + 32768;    // [32,4096]

    // 11 dispatches total
    k1_init_qproj<<<384, 256, 0, stream>>>(query, Wq, bq, qp, hist, cand, scctl);
    k2_hist_s1<<<384, 256, 0, stream>>>(prio, qp, Wk, S1bf, hist);
    scan_kernel<<<1, 1024, 0, stream>>>(hist, scctl);
    k4_compact<<<256, 256, 0, stream>>>(prio, cand, scctl);
    sort4096_kernel<<<2, 1024, 0, stream>>>(cand);
    k6_gather<<<256, 256, 0, stream>>>(buffer, cand, scctl, bsub, bsubT);
    k7_gemm_scores<<<dim3(32, 2, 2), 256, 0, stream>>>(S1bf, bsub, spart);
    k8_softmax<<<256, 256, 0, stream>>>(spart, attnbf);
    k9_gemmt_avg<<<640, 256, 0, stream>>>(attnbf, bsubT, Tpart, out_attnavg);
    ctx_reduce4_kernel<<<dim3(8, 16), 256, 0, stream>>>(Tpart, Wv, bv, ctx);
    k11_outproj<<<dim3(8, 16), 256, 0, stream>>>(ctx, Wo, bo, out_retrieved);
}